// Round 7
// baseline (19603.909 us; speedup 1.0000x reference)
//
#include <hip/hip_runtime.h>
#include <hip/hip_bf16.h>
#include <cstdint>
#include <cstddef>

#define SEQ 4096
#define HID 1024
#define G4  4096
#define NWG 64       // each WG owns 16 hidden units (1 per wave)
#define TPB 1024
#define UPL 64

typedef unsigned long long u64;

// ---------------- persistent device scratch ------------------------------------
__device__ float g_xg[(size_t)SEQ * G4];   // 64 MB: input-gate preactivations
__device__ float g_y [(size_t)SEQ * HID];  // 16 MB: bottom LSTM outputs
__device__ u64   g_hp [2][HID];            // (tag<<32 | h-bits), parity dbuf
__device__ u64   g_h2p[2][HID];            // top LSTM h pairs
__device__ u64   g_upxp[(size_t)UPL * HID];// sampled y rows as pairs
__device__ float g_bias2[HID];
__device__ float g_e[SEQ];
__device__ float g_p[SEQ];
__device__ float g_invden[SEQ];
__device__ float g_csum[64 * HID];

__global__ __launch_bounds__(256) void k_init()
{
  const int i = blockIdx.x * 256 + threadIdx.x;
  if (i < 2 * HID) {
    ((u64*)g_hp)[i]  = 0ull;
    ((u64*)g_h2p)[i] = 0ull;
  }
  for (int k = i; k < UPL * HID; k += gridDim.x * 256) g_upxp[k] = 0ull;
}

// -------- coherent access via agent-scope relaxed atomics ----------------------
__device__ __forceinline__ u64 atomLoad64(const u64* p) {
  return __hip_atomic_load(p, __ATOMIC_RELAXED, __HIP_MEMORY_SCOPE_AGENT);
}
__device__ __forceinline__ void atomStore64(u64* p, u64 v) {
  __hip_atomic_store(p, v, __ATOMIC_RELAXED, __HIP_MEMORY_SCOPE_AGENT);
}
__device__ __forceinline__ u64 packPair(float v, unsigned tag) {
  return ((u64)tag << 32) | (u64)__float_as_uint(v);
}
// poll with s_sleep backoff: one dependent chain, low fabric spam
__device__ __forceinline__ float pollPair(const u64* p, unsigned tg) {
  u64 v = atomLoad64(p);
  while ((unsigned)(v >> 32) != tg) {
    __builtin_amdgcn_s_sleep(1);
    v = atomLoad64(p);
  }
  return __uint_as_float((unsigned)v);
}

// ---------------- K1: xg = x @ bot_Wih^T + (bih + bhh), fp32 tiled GEMM --------
#define BMT 128
#define BNT 128
#define BKT 32

__global__ __launch_bounds__(256) void k_gemm_xg(const float* __restrict__ A,
                                                 const float* __restrict__ B,
                                                 const float* __restrict__ bias0,
                                                 const float* __restrict__ bias1)
{
  __shared__ float As[BKT][BMT + 4];
  __shared__ float Bs[BKT][BNT + 4];
  const int t  = threadIdx.x;
  const int bn = blockIdx.x;
  const int bm = blockIdx.y;
  const int m0 = (t & 15) * 8;
  const int n0 = (t >> 4) * 8;

  float acc[8][8];
#pragma unroll
  for (int i = 0; i < 8; i++)
#pragma unroll
    for (int j = 0; j < 8; j++) acc[i][j] = 0.f;

  for (int k0 = 0; k0 < 1024; k0 += BKT) {
#pragma unroll
    for (int i = 0; i < 4; i++) {
      const int idx = i * 256 + t;
      const int m   = idx >> 3;
      const int k4  = (idx & 7) << 2;
      const float4 av = *(const float4*)&A[(size_t)(bm * BMT + m) * 1024 + k0 + k4];
      As[k4 + 0][m] = av.x; As[k4 + 1][m] = av.y; As[k4 + 2][m] = av.z; As[k4 + 3][m] = av.w;
      const float4 bv = *(const float4*)&B[(size_t)(bn * BNT + m) * 1024 + k0 + k4];
      Bs[k4 + 0][m] = bv.x; Bs[k4 + 1][m] = bv.y; Bs[k4 + 2][m] = bv.z; Bs[k4 + 3][m] = bv.w;
    }
    __syncthreads();
#pragma unroll
    for (int k = 0; k < BKT; k++) {
      float a[8], b[8];
      *(float4*)&a[0] = *(const float4*)&As[k][m0];
      *(float4*)&a[4] = *(const float4*)&As[k][m0 + 4];
      *(float4*)&b[0] = *(const float4*)&Bs[k][n0];
      *(float4*)&b[4] = *(const float4*)&Bs[k][n0 + 4];
#pragma unroll
      for (int i = 0; i < 8; i++)
#pragma unroll
        for (int j = 0; j < 8; j++) acc[i][j] = fmaf(a[i], b[j], acc[i][j]);
    }
    __syncthreads();
  }

  float bb[8];
#pragma unroll
  for (int j = 0; j < 8; j++) {
    const int gc = bn * BNT + n0 + j;
    bb[j] = bias0[gc] + bias1[gc];
  }
#pragma unroll
  for (int i = 0; i < 8; i++) {
    const size_t off = (size_t)(bm * BMT + m0 + i) * G4 + bn * BNT + n0;
    float4 v0, v1;
    v0.x = acc[i][0] + bb[0]; v0.y = acc[i][1] + bb[1]; v0.z = acc[i][2] + bb[2]; v0.w = acc[i][3] + bb[3];
    v1.x = acc[i][4] + bb[4]; v1.y = acc[i][5] + bb[5]; v1.z = acc[i][6] + bb[6]; v1.w = acc[i][7] + bb[7];
    *(float4*)&g_xg[off]     = v0;
    *(float4*)&g_xg[off + 4] = v1;
  }
}

// ---------------- K2: persistent LSTM, single-trip tagged dataflow -------------
// Wave q of WG w owns hidden unit u = w*16+q. Lane l: gate g = l>>4, column
// segment j = l&15 (64 cols). Weights: 16 float4/lane in VGPRs. One poll word
// per THREAD (t <-> unit t of previous h). No barrier, no fence, no drain.

__device__ __forceinline__ void load_w16(float4* __restrict__ wv,
                                         const float* __restrict__ W,
                                         int row, int j)
{
  const float* wr = W + (size_t)row * HID + (j << 6);
#pragma unroll
  for (int k = 0; k < 16; k++) wv[k] = *(const float4*)&wr[((k + j) & 15) << 2];
}

__device__ __forceinline__ float dot16(const float4* __restrict__ wv,
                                       const float* __restrict__ hb, int j)
{
  float acc = 0.f;
#pragma unroll
  for (int k = 0; k < 16; k++) {
    const float4 hv = *(const float4*)&hb[((k + j) & 15) << 2];  // rotated
    acc = fmaf(wv[k].x, hv.x, acc);
    acc = fmaf(wv[k].y, hv.y, acc);
    acc = fmaf(wv[k].z, hv.z, acc);
    acc = fmaf(wv[k].w, hv.w, acc);
  }
  return acc;
}

__global__ __launch_bounds__(TPB, 4) void k_lstm(
    const float* __restrict__ bot_Whh,
    const float* __restrict__ top_Wih, const float* __restrict__ top_Whh,
    const float* __restrict__ top_bih, const float* __restrict__ top_bhh,
    const float* __restrict__ hw_b,    const float* __restrict__ cw_w,
    const float* __restrict__ cw_b,    const float* __restrict__ att_bias)
{
  const int w  = blockIdx.x;            // 0..63
  const int t  = threadIdx.x;           // 0..1023
  const int q  = t >> 6;                // wave 0..15
  const int l  = t & 63;
  const int g  = l >> 4;                // gate 0..3
  const int j  = l & 15;                // col segment 0..15
  const int u  = (w << 4) + q;          // owned hidden unit
  const int row = (g << 10) + u;        // gate*1024 + unit

  __shared__ float hl[2][HID];          // parity-double-buffered h stage
  __shared__ float xg2_lds[UPL][64];    // 16 units * 4 gates per WG

  float4 wv[16];
  load_w16(wv, bot_Whh, row, j);

  float c_state = 0.f;

  // ---- bottom LSTM: 4096 sequential steps ----
  for (int step = 0; step < SEQ; step++) {
    float xval = 0.f;
    if (j == 0) xval = g_xg[(size_t)step * G4 + row];   // overlaps the poll

    float* hc = hl[step & 1];
    if (step == 0) {
      hc[t] = 0.f;
    } else {
      hc[t] = pollPair(&g_hp[(step + 1) & 1][t], (unsigned)step);
    }
    __syncthreads();

    float acc = dot16(wv, &hc[j << 6], j);
    acc += __shfl_xor(acc, 1);
    acc += __shfl_xor(acc, 2);
    acc += __shfl_xor(acc, 4);
    acc += __shfl_xor(acc, 8);
    acc += xval;                         // xval==0 on j!=0 lanes

    const float gi = __shfl(acc, 0);
    const float gf = __shfl(acc, 16);
    const float gg = __shfl(acc, 32);
    const float go = __shfl(acc, 48);
    const float ii = 1.f / (1.f + expf(-gi));
    const float ff = 1.f / (1.f + expf(-gf));
    c_state = ff * c_state + ii * tanhf(gg);
    const float hh = (1.f / (1.f + expf(-go))) * tanhf(c_state);

    if (l == 0) {
      atomStore64(&g_hp[step & 1][u], packPair(hh, (unsigned)(step + 1)));
      g_y[(size_t)step * HID + u] = hh;
      if ((step & 63) == 63)
        atomStore64(&g_upxp[((size_t)(step >> 6) << 10) + u],
                    packPair(hh, (unsigned)((step >> 6) + 1)));
    }
  }

  // ---- top-LSTM input projection: xg2[s] = upx[s] @ top_Wih^T + bias ----
  load_w16(wv, top_Wih, row, j);
  float tb = 0.f;
  if (j == 0) tb = top_bih[row] + top_bhh[row];
  for (int s = 0; s < UPL; s++) {
    float* hc = hl[s & 1];
    hc[t] = pollPair(&g_upxp[((size_t)s << 10) + t], (unsigned)(s + 1));
    __syncthreads();
    float acc = dot16(wv, &hc[j << 6], j);
    acc += __shfl_xor(acc, 1);
    acc += __shfl_xor(acc, 2);
    acc += __shfl_xor(acc, 4);
    acc += __shfl_xor(acc, 8);
    if (j == 0) xg2_lds[s][(q << 2) + g] = acc + tb;
  }

  // ---- top recurrence: 64 steps ----
  load_w16(wv, top_Whh, row, j);
  c_state = 0.f;
  for (int s = 0; s < UPL; s++) {
    float* hc = hl[s & 1];
    if (s == 0) {
      hc[t] = 0.f;
    } else {
      hc[t] = pollPair(&g_h2p[(s + 1) & 1][t], (unsigned)s);
    }
    __syncthreads();
    float acc = dot16(wv, &hc[j << 6], j);
    acc += __shfl_xor(acc, 1);
    acc += __shfl_xor(acc, 2);
    acc += __shfl_xor(acc, 4);
    acc += __shfl_xor(acc, 8);
    acc += xg2_lds[s][(q << 2) + g];     // uniform within 16-lane group

    const float gi = __shfl(acc, 0);
    const float gf = __shfl(acc, 16);
    const float gg = __shfl(acc, 32);
    const float go = __shfl(acc, 48);
    const float ii = 1.f / (1.f + expf(-gi));
    const float ff = 1.f / (1.f + expf(-gf));
    c_state = ff * c_state + ii * tanhf(gg);
    const float hh = (1.f / (1.f + expf(-go))) * tanhf(c_state);

    if (l == 0)
      atomStore64(&g_h2p[s & 1][u], packPair(hh, (unsigned)(s + 1)));
  }

  // ---- bias2[u] = hw_b + cw_b + att_bias + ctx @ cw_w^T (ctx = h2 @ s=63) ----
  {
    float* hc = hl[0];
    hc[t] = pollPair(&g_h2p[1][t], (unsigned)UPL);
    __syncthreads();

    const float* cr = cw_w + (size_t)u * HID + (l << 4);
    const float* hr = &hc[l << 4];
    float a2 = 0.f;
#pragma unroll
    for (int k4 = 0; k4 < 4; k4++) {
      const float4 cv = *(const float4*)&cr[k4 << 2];
      const float4 hv = *(const float4*)&hr[k4 << 2];
      a2 = fmaf(cv.x, hv.x, a2);
      a2 = fmaf(cv.y, hv.y, a2);
      a2 = fmaf(cv.z, hv.z, a2);
      a2 = fmaf(cv.w, hv.w, a2);
    }
    a2 += __shfl_xor(a2, 1);
    a2 += __shfl_xor(a2, 2);
    a2 += __shfl_xor(a2, 4);
    a2 += __shfl_xor(a2, 8);
    a2 += __shfl_xor(a2, 16);
    a2 += __shfl_xor(a2, 32);
    if (l == 0) g_bias2[u] = a2 + hw_b[u] + cw_b[u] + att_bias[u];
  }
}

// ---------------- K3: e[t] = sum_j v2s_w[j]*tanh(y_t . hw_w[j] + bias2[j]) ----
__global__ __launch_bounds__(256) void k_attn_e(const float* __restrict__ hw_w,
                                                const float* __restrict__ v2s_w,
                                                const float* __restrict__ v2s_b)
{
  __shared__ float ys[16][1028];
  __shared__ float ws[16][1028];
  const int b  = blockIdx.x;
  const int t  = threadIdx.x;
  const int rg = t >> 6;
  const int fg = (t >> 4) & 3;
  const int ks = t & 15;

#pragma unroll
  for (int i = 0; i < 16; i++) {
    const int idx = i * 256 + t;
    const int r   = idx >> 8;
    const int c4  = (idx & 255) << 2;
    *(float4*)&ys[r][c4] = *(const float4*)&g_y[(size_t)((b << 4) + r) * HID + c4];
  }

  float e_acc[4] = {0.f, 0.f, 0.f, 0.f};
  for (int f0 = 0; f0 < HID; f0 += 16) {
    __syncthreads();
#pragma unroll
    for (int i = 0; i < 16; i++) {
      const int idx = i * 256 + t;
      const int r   = idx >> 8;
      const int c4  = (idx & 255) << 2;
      *(float4*)&ws[r][c4] = *(const float4*)&hw_w[(size_t)(f0 + r) * HID + c4];
    }
    __syncthreads();

    float acc[4][4];
#pragma unroll
    for (int u = 0; u < 4; u++)
#pragma unroll
      for (int v = 0; v < 4; v++) acc[u][v] = 0.f;

#pragma unroll
    for (int m = 0; m < 16; m++) {
      const int k4 = (ks << 6) + (((m + ks) & 15) << 2);
      float4 av[4], bv[4];
#pragma unroll
      for (int u = 0; u < 4; u++) av[u] = *(const float4*)&ys[(rg << 2) + u][k4];
#pragma unroll
      for (int v = 0; v < 4; v++) bv[v] = *(const float4*)&ws[(fg << 2) + v][k4];
#pragma unroll
      for (int u = 0; u < 4; u++)
#pragma unroll
        for (int v = 0; v < 4; v++) {
          acc[u][v] = fmaf(av[u].x, bv[v].x, acc[u][v]);
          acc[u][v] = fmaf(av[u].y, bv[v].y, acc[u][v]);
          acc[u][v] = fmaf(av[u].z, bv[v].z, acc[u][v]);
          acc[u][v] = fmaf(av[u].w, bv[v].w, acc[u][v]);
        }
    }
#pragma unroll
    for (int u = 0; u < 4; u++)
#pragma unroll
      for (int v = 0; v < 4; v++) {
        float s2 = acc[u][v];
        s2 += __shfl_xor(s2, 8);
        s2 += __shfl_xor(s2, 4);
        s2 += __shfl_xor(s2, 2);
        s2 += __shfl_xor(s2, 1);
        acc[u][v] = s2;
      }
    if (ks == 0) {
#pragma unroll
      for (int v = 0; v < 4; v++) {
        const int jj = f0 + (fg << 2) + v;
        const float bias = g_bias2[jj];
        const float vw   = v2s_w[jj];
#pragma unroll
        for (int u = 0; u < 4; u++)
          e_acc[u] += vw * tanhf(acc[u][v] + bias);
      }
    }
  }
#pragma unroll
  for (int u = 0; u < 4; u++) {
    float s2 = e_acc[u];
    s2 += __shfl_xor(s2, 16);
    s2 += __shfl_xor(s2, 32);
    if (fg == 0 && ks == 0) g_e[(b << 4) + (rg << 2) + u] = s2 + v2s_b[0];
  }
}

// ---------------- K4a: p = exp(e - max e); invden = 1/cumsum(p) --------------
__global__ __launch_bounds__(1024) void k_softmax()
{
  const int t  = threadIdx.x;
  const int ln = t & 63;
  const int wv = t >> 6;
  __shared__ float sred[16];
  __shared__ float soff[16];
  __shared__ float sM;

  const float4 ev = *(const float4*)&g_e[t << 2];
  float mx = fmaxf(fmaxf(ev.x, ev.y), fmaxf(ev.z, ev.w));
#pragma unroll
  for (int d = 32; d >= 1; d >>= 1) mx = fmaxf(mx, __shfl_xor(mx, d));
  if (ln == 0) sred[wv] = mx;
  __syncthreads();
  if (t == 0) {
    float m2 = sred[0];
    for (int i = 1; i < 16; i++) m2 = fmaxf(m2, sred[i]);
    sM = m2;
  }
  __syncthreads();
  const float M = sM;
  float4 pv;
  pv.x = expf(ev.x - M); pv.y = expf(ev.y - M); pv.z = expf(ev.z - M); pv.w = expf(ev.w - M);
  *(float4*)&g_p[t << 2] = pv;

  const float s = pv.x + pv.y + pv.z + pv.w;
  float ps = s;
#pragma unroll
  for (int d = 1; d < 64; d <<= 1) {
    const float v = __shfl_up(ps, d);
    if (ln >= d) ps += v;
  }
  __syncthreads();
  if (ln == 63) sred[wv] = ps;
  __syncthreads();
  if (t == 0) {
    float r = 0.f;
    for (int i = 0; i < 16; i++) { soff[i] = r; r += sred[i]; }
  }
  __syncthreads();
  const float base = soff[wv] + (ps - s);
  const float d0 = base + pv.x;
  const float d1 = d0 + pv.y;
  const float d2 = d1 + pv.z;
  const float d3 = d2 + pv.w;
  float4 iv;
  iv.x = 1.f / d0; iv.y = 1.f / d1; iv.z = 1.f / d2; iv.w = 1.f / d3;
  *(float4*)&g_invden[t << 2] = iv;
}

// ---------------- K4b/c/d: chunked column scan of cumsum(p*y)/den ------------
__global__ __launch_bounds__(256) void k_csum()
{
  const int ch = blockIdx.x;
  const int t  = threadIdx.x;
  float ax = 0.f, ay = 0.f, az = 0.f, aw = 0.f;
  for (int r = 0; r < 64; r++) {
    const int row = (ch << 6) + r;
    const float pr = g_p[row];
    const float4 yv = *(const float4*)&g_y[(size_t)row * HID + (t << 2)];
    ax = fmaf(pr, yv.x, ax); ay = fmaf(pr, yv.y, ay);
    az = fmaf(pr, yv.z, az); aw = fmaf(pr, yv.w, aw);
  }
  float4 o; o.x = ax; o.y = ay; o.z = az; o.w = aw;
  *(float4*)&g_csum[(ch << 10) + (t << 2)] = o;
}

__global__ __launch_bounds__(256) void k_cscan()
{
  const int c = blockIdx.x * 256 + threadIdx.x;
  float run = 0.f;
  for (int ch = 0; ch < 64; ch++) {
    const float v = g_csum[(ch << 10) + c];
    g_csum[(ch << 10) + c] = run;
    run += v;
  }
}

__global__ __launch_bounds__(256) void k_final(float* __restrict__ out)
{
  const int ch = blockIdx.x;
  const int t  = threadIdx.x;
  float4 run = *(const float4*)&g_csum[(ch << 10) + (t << 2)];
  for (int r = 0; r < 64; r++) {
    const int row = (ch << 6) + r;
    const float pr = g_p[row];
    const float iv = g_invden[row];
    const float4 yv = *(const float4*)&g_y[(size_t)row * HID + (t << 2)];
    run.x = fmaf(pr, yv.x, run.x);
    run.y = fmaf(pr, yv.y, run.y);
    run.z = fmaf(pr, yv.z, run.z);
    run.w = fmaf(pr, yv.w, run.w);
    float4 ov;
    ov.x = run.x * iv; ov.y = run.y * iv; ov.z = run.z * iv; ov.w = run.w * iv;
    *(float4*)&out[(size_t)row * HID + (t << 2)] = ov;
  }
}

// ---------------- host launch --------------------------------------------------
extern "C" void kernel_launch(void* const* d_in, const int* in_sizes, int n_in,
                              void* d_out, int out_size, void* d_ws, size_t ws_size,
                              hipStream_t stream)
{
  (void)in_sizes; (void)n_in; (void)d_ws; (void)ws_size; (void)out_size;

  const float* x        = (const float*)d_in[0];
  const float* bot_Wih  = (const float*)d_in[1];
  const float* bot_Whh  = (const float*)d_in[2];
  const float* bot_bih  = (const float*)d_in[3];
  const float* bot_bhh  = (const float*)d_in[4];
  const float* top_Wih  = (const float*)d_in[5];
  const float* top_Whh  = (const float*)d_in[6];
  const float* top_bih  = (const float*)d_in[7];
  const float* top_bhh  = (const float*)d_in[8];
  const float* hw_w     = (const float*)d_in[9];
  const float* hw_b     = (const float*)d_in[10];
  const float* cw_w     = (const float*)d_in[11];
  const float* cw_b     = (const float*)d_in[12];
  const float* att_bias = (const float*)d_in[13];
  const float* v2s_w    = (const float*)d_in[14];
  const float* v2s_b    = (const float*)d_in[15];
  float* out = (float*)d_out;

  k_init<<<dim3(64), dim3(256), 0, stream>>>();
  k_gemm_xg<<<dim3(32, 32), dim3(256), 0, stream>>>(x, bot_Wih, bot_bih, bot_bhh);
  k_lstm<<<dim3(NWG), dim3(TPB), 0, stream>>>(bot_Whh, top_Wih, top_Whh,
                                              top_bih, top_bhh,
                                              hw_b, cw_w, cw_b, att_bias);
  k_attn_e<<<dim3(256), dim3(256), 0, stream>>>(hw_w, v2s_w, v2s_b);
  k_softmax<<<dim3(1), dim3(1024), 0, stream>>>();
  k_csum<<<dim3(64), dim3(256), 0, stream>>>();
  k_cscan<<<dim3(4), dim3(256), 0, stream>>>();
  k_final<<<dim3(64), dim3(256), 0, stream>>>(out);
}

// Round 8
// 12498.833 us; speedup vs baseline: 1.5685x; 1.5685x over previous
//
#include <hip/hip_runtime.h>
#include <hip/hip_bf16.h>
#include <cstdint>
#include <cstddef>

#define SEQ 4096
#define HID 1024
#define G4  4096
#define NWG 64       // each WG owns 16 hidden units (1 per wave)
#define TPB 1024
#define UPL 64

typedef unsigned long long u64;

// ---------------- persistent device scratch ------------------------------------
__device__ float    g_xg[(size_t)SEQ * G4];   // 64 MB: input-gate preactivations
__device__ float    g_y [(size_t)SEQ * HID];  // 16 MB: bottom LSTM outputs
__device__ float    g_hd[2][HID];             // untagged h data, parity dbuf
__device__ unsigned g_arrive[NWG][16];        // per-WG step flags, 64B padded
__device__ u64      g_h2p[2][HID];            // top LSTM h tagged pairs
__device__ u64      g_upxp[(size_t)UPL * HID];// sampled y rows as tagged pairs
__device__ float    g_bias2[HID];
__device__ float    g_e[SEQ];
__device__ float    g_p[SEQ];
__device__ float    g_invden[SEQ];
__device__ float    g_csum[64 * HID];

__global__ __launch_bounds__(256) void k_init()
{
  const int i = blockIdx.x * 256 + threadIdx.x;
  if (i < 2 * HID) ((u64*)g_h2p)[i] = 0ull;
  if (i < NWG * 16) ((unsigned*)g_arrive)[i] = 0u;
  for (int k = i; k < UPL * HID; k += gridDim.x * 256) g_upxp[k] = 0ull;
}

// -------- coherent access via agent-scope relaxed atomics ----------------------
__device__ __forceinline__ u64 atomLoad64(const u64* p) {
  return __hip_atomic_load(p, __ATOMIC_RELAXED, __HIP_MEMORY_SCOPE_AGENT);
}
__device__ __forceinline__ void atomStore64(u64* p, u64 v) {
  __hip_atomic_store(p, v, __ATOMIC_RELAXED, __HIP_MEMORY_SCOPE_AGENT);
}
__device__ __forceinline__ float atomLoadF(const float* p) {
  return __hip_atomic_load(p, __ATOMIC_RELAXED, __HIP_MEMORY_SCOPE_AGENT);
}
__device__ __forceinline__ void atomStoreF(float* p, float v) {
  __hip_atomic_store(p, v, __ATOMIC_RELAXED, __HIP_MEMORY_SCOPE_AGENT);
}
__device__ __forceinline__ unsigned atomLoadU(const unsigned* p) {
  return __hip_atomic_load(p, __ATOMIC_RELAXED, __HIP_MEMORY_SCOPE_AGENT);
}
__device__ __forceinline__ void atomStoreU(unsigned* p, unsigned v) {
  __hip_atomic_store(p, v, __ATOMIC_RELAXED, __HIP_MEMORY_SCOPE_AGENT);
}
__device__ __forceinline__ u64 packPair(float v, unsigned tag) {
  return ((u64)tag << 32) | (u64)__float_as_uint(v);
}
__device__ __forceinline__ float pollPair(const u64* p, unsigned tg) {
  u64 v = atomLoad64(p);
  while ((unsigned)(v >> 32) != tg) {
    __builtin_amdgcn_s_sleep(2);
    v = atomLoad64(p);
  }
  return __uint_as_float((unsigned)v);
}

// ---------------- K1: xg = x @ bot_Wih^T + (bih + bhh), fp32 tiled GEMM --------
#define BMT 128
#define BNT 128
#define BKT 32

__global__ __launch_bounds__(256) void k_gemm_xg(const float* __restrict__ A,
                                                 const float* __restrict__ B,
                                                 const float* __restrict__ bias0,
                                                 const float* __restrict__ bias1)
{
  __shared__ float As[BKT][BMT + 4];
  __shared__ float Bs[BKT][BNT + 4];
  const int t  = threadIdx.x;
  const int bn = blockIdx.x;
  const int bm = blockIdx.y;
  const int m0 = (t & 15) * 8;
  const int n0 = (t >> 4) * 8;

  float acc[8][8];
#pragma unroll
  for (int i = 0; i < 8; i++)
#pragma unroll
    for (int j = 0; j < 8; j++) acc[i][j] = 0.f;

  for (int k0 = 0; k0 < 1024; k0 += BKT) {
#pragma unroll
    for (int i = 0; i < 4; i++) {
      const int idx = i * 256 + t;
      const int m   = idx >> 3;
      const int k4  = (idx & 7) << 2;
      const float4 av = *(const float4*)&A[(size_t)(bm * BMT + m) * 1024 + k0 + k4];
      As[k4 + 0][m] = av.x; As[k4 + 1][m] = av.y; As[k4 + 2][m] = av.z; As[k4 + 3][m] = av.w;
      const float4 bv = *(const float4*)&B[(size_t)(bn * BNT + m) * 1024 + k0 + k4];
      Bs[k4 + 0][m] = bv.x; Bs[k4 + 1][m] = bv.y; Bs[k4 + 2][m] = bv.z; Bs[k4 + 3][m] = bv.w;
    }
    __syncthreads();
#pragma unroll
    for (int k = 0; k < BKT; k++) {
      float a[8], b[8];
      *(float4*)&a[0] = *(const float4*)&As[k][m0];
      *(float4*)&a[4] = *(const float4*)&As[k][m0 + 4];
      *(float4*)&b[0] = *(const float4*)&Bs[k][n0];
      *(float4*)&b[4] = *(const float4*)&Bs[k][n0 + 4];
#pragma unroll
      for (int i = 0; i < 8; i++)
#pragma unroll
        for (int j = 0; j < 8; j++) acc[i][j] = fmaf(a[i], b[j], acc[i][j]);
    }
    __syncthreads();
  }

  float bb[8];
#pragma unroll
  for (int j = 0; j < 8; j++) {
    const int gc = bn * BNT + n0 + j;
    bb[j] = bias0[gc] + bias1[gc];
  }
#pragma unroll
  for (int i = 0; i < 8; i++) {
    const size_t off = (size_t)(bm * BMT + m0 + i) * G4 + bn * BNT + n0;
    float4 v0, v1;
    v0.x = acc[i][0] + bb[0]; v0.y = acc[i][1] + bb[1]; v0.z = acc[i][2] + bb[2]; v0.w = acc[i][3] + bb[3];
    v1.x = acc[i][4] + bb[4]; v1.y = acc[i][5] + bb[5]; v1.z = acc[i][6] + bb[6]; v1.w = acc[i][7] + bb[7];
    *(float4*)&g_xg[off]     = v0;
    *(float4*)&g_xg[off + 4] = v1;
  }
}

// ---------------- K2: persistent LSTM, flat flag-barrier dataflow --------------
// Wave q of WG w owns hidden unit u = w*16+q. Lane l: gate g = l>>4, column
// segment j = l&15 (64 cols). Weights: 16 float4/lane in VGPRs.
// Sync: per-WG padded flag; ONLY wave 0 polls (64 lanes x 64 WGs = 4096 pollers,
// one cache line each). Data is untagged, loaded exactly once per step.

__device__ __forceinline__ void load_w16(float4* __restrict__ wv,
                                         const float* __restrict__ W,
                                         int row, int j)
{
  const float* wr = W + (size_t)row * HID + (j << 6);
#pragma unroll
  for (int k = 0; k < 16; k++) wv[k] = *(const float4*)&wr[((k + j) & 15) << 2];
}

__device__ __forceinline__ float dot16(const float4* __restrict__ wv,
                                       const float* __restrict__ hb, int j)
{
  float acc = 0.f;
#pragma unroll
  for (int k = 0; k < 16; k++) {
    const float4 hv = *(const float4*)&hb[((k + j) & 15) << 2];  // rotated
    acc = fmaf(wv[k].x, hv.x, acc);
    acc = fmaf(wv[k].y, hv.y, acc);
    acc = fmaf(wv[k].z, hv.z, acc);
    acc = fmaf(wv[k].w, hv.w, acc);
  }
  return acc;
}

__global__ __launch_bounds__(TPB, 4) void k_lstm(
    const float* __restrict__ bot_Whh,
    const float* __restrict__ top_Wih, const float* __restrict__ top_Whh,
    const float* __restrict__ top_bih, const float* __restrict__ top_bhh,
    const float* __restrict__ hw_b,    const float* __restrict__ cw_w,
    const float* __restrict__ cw_b,    const float* __restrict__ att_bias)
{
  const int w  = blockIdx.x;            // 0..63
  const int t  = threadIdx.x;           // 0..1023
  const int q  = t >> 6;                // wave 0..15
  const int l  = t & 63;
  const int g  = l >> 4;                // gate 0..3
  const int j  = l & 15;                // col segment 0..15
  const int u  = (w << 4) + q;          // owned hidden unit
  const int row = (g << 10) + u;        // gate*1024 + unit

  __shared__ float hl[2][HID];          // parity-double-buffered h stage
  __shared__ float xg2_lds[UPL][64];    // 16 units * 4 gates per WG

  float4 wv[16];
  load_w16(wv, bot_Whh, row, j);

  float c_state = 0.f;

  // ---- bottom LSTM: 4096 sequential steps ----
  for (int step = 0; step < SEQ; step++) {
    float xval = 0.f;
    if (j == 0) xval = g_xg[(size_t)step * G4 + row];   // overlaps the wait

    float* hc = hl[step & 1];
    if (step == 0) {
      hc[t] = 0.f;
      __syncthreads();
    } else {
      if (t < NWG) {                    // wave 0: lane t watches WG t's flag
        const unsigned tgt = (unsigned)step;
        unsigned v = atomLoadU(&g_arrive[t][0]);
        while (v < tgt) {
          __builtin_amdgcn_s_sleep(2);
          v = atomLoadU(&g_arrive[t][0]);
        }
      }
      __syncthreads();                  // flags seen -> data at LLC
      hc[t] = atomLoadF(&g_hd[(step + 1) & 1][t]);   // one-shot load
      __syncthreads();                  // hc staged
    }

    float acc = dot16(wv, &hc[j << 6], j);
    acc += __shfl_xor(acc, 1);
    acc += __shfl_xor(acc, 2);
    acc += __shfl_xor(acc, 4);
    acc += __shfl_xor(acc, 8);
    acc += xval;                         // xval==0 on j!=0 lanes

    const float gi = __shfl(acc, 0);
    const float gf = __shfl(acc, 16);
    const float gg = __shfl(acc, 32);
    const float go = __shfl(acc, 48);
    const float ii = 1.f / (1.f + expf(-gi));
    const float ff = 1.f / (1.f + expf(-gf));
    c_state = ff * c_state + ii * tanhf(gg);
    const float hh = (1.f / (1.f + expf(-go))) * tanhf(c_state);

    if (l == 0) {
      atomStoreF(&g_hd[step & 1][u], hh);
      g_y[(size_t)step * HID + u] = hh;
      if ((step & 63) == 63)
        atomStore64(&g_upxp[((size_t)(step >> 6) << 10) + u],
                    packPair(hh, (unsigned)((step >> 6) + 1)));
    }
    __syncthreads();                     // drain all waves' stores (vmcnt 0)
    if (t == 0) atomStoreU(&g_arrive[w][0], (unsigned)(step + 1));
  }

  // ---- top-LSTM input projection: xg2[s] = upx[s] @ top_Wih^T + bias ----
  load_w16(wv, top_Wih, row, j);
  float tb = 0.f;
  if (j == 0) tb = top_bih[row] + top_bhh[row];
  for (int s = 0; s < UPL; s++) {
    float* hc = hl[s & 1];
    hc[t] = pollPair(&g_upxp[((size_t)s << 10) + t], (unsigned)(s + 1));
    __syncthreads();
    float acc = dot16(wv, &hc[j << 6], j);
    acc += __shfl_xor(acc, 1);
    acc += __shfl_xor(acc, 2);
    acc += __shfl_xor(acc, 4);
    acc += __shfl_xor(acc, 8);
    if (j == 0) xg2_lds[s][(q << 2) + g] = acc + tb;
    __syncthreads();
  }

  // ---- top recurrence: 64 steps (tagged pairs; tiny) ----
  load_w16(wv, top_Whh, row, j);
  c_state = 0.f;
  for (int s = 0; s < UPL; s++) {
    float* hc = hl[s & 1];
    if (s == 0) {
      hc[t] = 0.f;
    } else {
      hc[t] = pollPair(&g_h2p[(s + 1) & 1][t], (unsigned)s);
    }
    __syncthreads();
    float acc = dot16(wv, &hc[j << 6], j);
    acc += __shfl_xor(acc, 1);
    acc += __shfl_xor(acc, 2);
    acc += __shfl_xor(acc, 4);
    acc += __shfl_xor(acc, 8);
    acc += xg2_lds[s][(q << 2) + g];     // uniform within 16-lane group

    const float gi = __shfl(acc, 0);
    const float gf = __shfl(acc, 16);
    const float gg = __shfl(acc, 32);
    const float go = __shfl(acc, 48);
    const float ii = 1.f / (1.f + expf(-gi));
    const float ff = 1.f / (1.f + expf(-gf));
    c_state = ff * c_state + ii * tanhf(gg);
    const float hh = (1.f / (1.f + expf(-go))) * tanhf(c_state);

    if (l == 0)
      atomStore64(&g_h2p[s & 1][u], packPair(hh, (unsigned)(s + 1)));
  }

  // ---- bias2[u] = hw_b + cw_b + att_bias + ctx @ cw_w^T (ctx = h2 @ s=63) ----
  {
    float* hc = hl[0];
    hc[t] = pollPair(&g_h2p[1][t], (unsigned)UPL);
    __syncthreads();

    const float* cr = cw_w + (size_t)u * HID + (l << 4);
    const float* hr = &hc[l << 4];
    float a2 = 0.f;
#pragma unroll
    for (int k4 = 0; k4 < 4; k4++) {
      const float4 cv = *(const float4*)&cr[k4 << 2];
      const float4 hv = *(const float4*)&hr[k4 << 2];
      a2 = fmaf(cv.x, hv.x, a2);
      a2 = fmaf(cv.y, hv.y, a2);
      a2 = fmaf(cv.z, hv.z, a2);
      a2 = fmaf(cv.w, hv.w, a2);
    }
    a2 += __shfl_xor(a2, 1);
    a2 += __shfl_xor(a2, 2);
    a2 += __shfl_xor(a2, 4);
    a2 += __shfl_xor(a2, 8);
    a2 += __shfl_xor(a2, 16);
    a2 += __shfl_xor(a2, 32);
    if (l == 0) g_bias2[u] = a2 + hw_b[u] + cw_b[u] + att_bias[u];
  }
}

// ---------------- K3: e[t] = sum_j v2s_w[j]*tanh(y_t . hw_w[j] + bias2[j]) ----
__global__ __launch_bounds__(256) void k_attn_e(const float* __restrict__ hw_w,
                                                const float* __restrict__ v2s_w,
                                                const float* __restrict__ v2s_b)
{
  __shared__ float ys[16][1028];
  __shared__ float ws[16][1028];
  const int b  = blockIdx.x;
  const int t  = threadIdx.x;
  const int rg = t >> 6;
  const int fg = (t >> 4) & 3;
  const int ks = t & 15;

#pragma unroll
  for (int i = 0; i < 16; i++) {
    const int idx = i * 256 + t;
    const int r   = idx >> 8;
    const int c4  = (idx & 255) << 2;
    *(float4*)&ys[r][c4] = *(const float4*)&g_y[(size_t)((b << 4) + r) * HID + c4];
  }

  float e_acc[4] = {0.f, 0.f, 0.f, 0.f};
  for (int f0 = 0; f0 < HID; f0 += 16) {
    __syncthreads();
#pragma unroll
    for (int i = 0; i < 16; i++) {
      const int idx = i * 256 + t;
      const int r   = idx >> 8;
      const int c4  = (idx & 255) << 2;
      *(float4*)&ws[r][c4] = *(const float4*)&hw_w[(size_t)(f0 + r) * HID + c4];
    }
    __syncthreads();

    float acc[4][4];
#pragma unroll
    for (int u = 0; u < 4; u++)
#pragma unroll
      for (int v = 0; v < 4; v++) acc[u][v] = 0.f;

#pragma unroll
    for (int m = 0; m < 16; m++) {
      const int k4 = (ks << 6) + (((m + ks) & 15) << 2);
      float4 av[4], bv[4];
#pragma unroll
      for (int u = 0; u < 4; u++) av[u] = *(const float4*)&ys[(rg << 2) + u][k4];
#pragma unroll
      for (int v = 0; v < 4; v++) bv[v] = *(const float4*)&ws[(fg << 2) + v][k4];
#pragma unroll
      for (int u = 0; u < 4; u++)
#pragma unroll
        for (int v = 0; v < 4; v++) {
          acc[u][v] = fmaf(av[u].x, bv[v].x, acc[u][v]);
          acc[u][v] = fmaf(av[u].y, bv[v].y, acc[u][v]);
          acc[u][v] = fmaf(av[u].z, bv[v].z, acc[u][v]);
          acc[u][v] = fmaf(av[u].w, bv[v].w, acc[u][v]);
        }
    }
#pragma unroll
    for (int u = 0; u < 4; u++)
#pragma unroll
      for (int v = 0; v < 4; v++) {
        float s2 = acc[u][v];
        s2 += __shfl_xor(s2, 8);
        s2 += __shfl_xor(s2, 4);
        s2 += __shfl_xor(s2, 2);
        s2 += __shfl_xor(s2, 1);
        acc[u][v] = s2;
      }
    if (ks == 0) {
#pragma unroll
      for (int v = 0; v < 4; v++) {
        const int jj = f0 + (fg << 2) + v;
        const float bias = g_bias2[jj];
        const float vw   = v2s_w[jj];
#pragma unroll
        for (int u = 0; u < 4; u++)
          e_acc[u] += vw * tanhf(acc[u][v] + bias);
      }
    }
  }
#pragma unroll
  for (int u = 0; u < 4; u++) {
    float s2 = e_acc[u];
    s2 += __shfl_xor(s2, 16);
    s2 += __shfl_xor(s2, 32);
    if (fg == 0 && ks == 0) g_e[(b << 4) + (rg << 2) + u] = s2 + v2s_b[0];
  }
}

// ---------------- K4a: p = exp(e - max e); invden = 1/cumsum(p) --------------
__global__ __launch_bounds__(1024) void k_softmax()
{
  const int t  = threadIdx.x;
  const int ln = t & 63;
  const int wv = t >> 6;
  __shared__ float sred[16];
  __shared__ float soff[16];
  __shared__ float sM;

  const float4 ev = *(const float4*)&g_e[t << 2];
  float mx = fmaxf(fmaxf(ev.x, ev.y), fmaxf(ev.z, ev.w));
#pragma unroll
  for (int d = 32; d >= 1; d >>= 1) mx = fmaxf(mx, __shfl_xor(mx, d));
  if (ln == 0) sred[wv] = mx;
  __syncthreads();
  if (t == 0) {
    float m2 = sred[0];
    for (int i = 1; i < 16; i++) m2 = fmaxf(m2, sred[i]);
    sM = m2;
  }
  __syncthreads();
  const float M = sM;
  float4 pv;
  pv.x = expf(ev.x - M); pv.y = expf(ev.y - M); pv.z = expf(ev.z - M); pv.w = expf(ev.w - M);
  *(float4*)&g_p[t << 2] = pv;

  const float s = pv.x + pv.y + pv.z + pv.w;
  float ps = s;
#pragma unroll
  for (int d = 1; d < 64; d <<= 1) {
    const float v = __shfl_up(ps, d);
    if (ln >= d) ps += v;
  }
  __syncthreads();
  if (ln == 63) sred[wv] = ps;
  __syncthreads();
  if (t == 0) {
    float r = 0.f;
    for (int i = 0; i < 16; i++) { soff[i] = r; r += sred[i]; }
  }
  __syncthreads();
  const float base = soff[wv] + (ps - s);
  const float d0 = base + pv.x;
  const float d1 = d0 + pv.y;
  const float d2 = d1 + pv.z;
  const float d3 = d2 + pv.w;
  float4 iv;
  iv.x = 1.f / d0; iv.y = 1.f / d1; iv.z = 1.f / d2; iv.w = 1.f / d3;
  *(float4*)&g_invden[t << 2] = iv;
}

// ---------------- K4b/c/d: chunked column scan of cumsum(p*y)/den ------------
__global__ __launch_bounds__(256) void k_csum()
{
  const int ch = blockIdx.x;
  const int t  = threadIdx.x;
  float ax = 0.f, ay = 0.f, az = 0.f, aw = 0.f;
  for (int r = 0; r < 64; r++) {
    const int row = (ch << 6) + r;
    const float pr = g_p[row];
    const float4 yv = *(const float4*)&g_y[(size_t)row * HID + (t << 2)];
    ax = fmaf(pr, yv.x, ax); ay = fmaf(pr, yv.y, ay);
    az = fmaf(pr, yv.z, az); aw = fmaf(pr, yv.w, aw);
  }
  float4 o; o.x = ax; o.y = ay; o.z = az; o.w = aw;
  *(float4*)&g_csum[(ch << 10) + (t << 2)] = o;
}

__global__ __launch_bounds__(256) void k_cscan()
{
  const int c = blockIdx.x * 256 + threadIdx.x;
  float run = 0.f;
  for (int ch = 0; ch < 64; ch++) {
    const float v = g_csum[(ch << 10) + c];
    g_csum[(ch << 10) + c] = run;
    run += v;
  }
}

__global__ __launch_bounds__(256) void k_final(float* __restrict__ out)
{
  const int ch = blockIdx.x;
  const int t  = threadIdx.x;
  float4 run = *(const float4*)&g_csum[(ch << 10) + (t << 2)];
  for (int r = 0; r < 64; r++) {
    const int row = (ch << 6) + r;
    const float pr = g_p[row];
    const float iv = g_invden[row];
    const float4 yv = *(const float4*)&g_y[(size_t)row * HID + (t << 2)];
    run.x = fmaf(pr, yv.x, run.x);
    run.y = fmaf(pr, yv.y, run.y);
    run.z = fmaf(pr, yv.z, run.z);
    run.w = fmaf(pr, yv.w, run.w);
    float4 ov;
    ov.x = run.x * iv; ov.y = run.y * iv; ov.z = run.z * iv; ov.w = run.w * iv;
    *(float4*)&out[(size_t)row * HID + (t << 2)] = ov;
  }
}

// ---------------- host launch --------------------------------------------------
extern "C" void kernel_launch(void* const* d_in, const int* in_sizes, int n_in,
                              void* d_out, int out_size, void* d_ws, size_t ws_size,
                              hipStream_t stream)
{
  (void)in_sizes; (void)n_in; (void)d_ws; (void)ws_size; (void)out_size;

  const float* x        = (const float*)d_in[0];
  const float* bot_Wih  = (const float*)d_in[1];
  const float* bot_Whh  = (const float*)d_in[2];
  const float* bot_bih  = (const float*)d_in[3];
  const float* bot_bhh  = (const float*)d_in[4];
  const float* top_Wih  = (const float*)d_in[5];
  const float* top_Whh  = (const float*)d_in[6];
  const float* top_bih  = (const float*)d_in[7];
  const float* top_bhh  = (const float*)d_in[8];
  const float* hw_w     = (const float*)d_in[9];
  const float* hw_b     = (const float*)d_in[10];
  const float* cw_w     = (const float*)d_in[11];
  const float* cw_b     = (const float*)d_in[12];
  const float* att_bias = (const float*)d_in[13];
  const float* v2s_w    = (const float*)d_in[14];
  const float* v2s_b    = (const float*)d_in[15];
  float* out = (float*)d_out;

  k_init<<<dim3(64), dim3(256), 0, stream>>>();
  k_gemm_xg<<<dim3(32, 32), dim3(256), 0, stream>>>(x, bot_Wih, bot_bih, bot_bhh);
  k_lstm<<<dim3(NWG), dim3(TPB), 0, stream>>>(bot_Whh, top_Wih, top_Whh,
                                              top_bih, top_bhh,
                                              hw_b, cw_w, cw_b, att_bias);
  k_attn_e<<<dim3(256), dim3(256), 0, stream>>>(hw_w, v2s_w, v2s_b);
  k_softmax<<<dim3(1), dim3(1024), 0, stream>>>();
  k_csum<<<dim3(64), dim3(256), 0, stream>>>();
  k_cscan<<<dim3(4), dim3(256), 0, stream>>>();
  k_final<<<dim3(64), dim3(256), 0, stream>>>(out);
}

// Round 9
// 12306.799 us; speedup vs baseline: 1.5929x; 1.0156x over previous
//
#include <hip/hip_runtime.h>
#include <hip/hip_bf16.h>
#include <cstdint>
#include <cstddef>

#define SEQ 4096
#define HID 1024
#define G4  4096
#define NWG 64       // each WG owns 16 hidden units (1 per wave)
#define TPB 1024
#define UPL 64

typedef unsigned long long u64;

// ---------------- persistent device scratch ------------------------------------
__device__ float g_xg[(size_t)SEQ * G4];       // 64 MB: input preactivations
__device__ float g_y [(size_t)SEQ * HID];      // 16 MB: bottom LSTM outputs
__device__ u64   g_hstep[(size_t)SEQ * HID];   // 32 MB: (tag<<32|h) per (step,unit)
__device__ u64   g_h2p[2][HID];                // top LSTM h tagged pairs
__device__ u64   g_upxp[(size_t)UPL * HID];    // sampled y rows as tagged pairs
__device__ float g_bias2[HID];
__device__ float g_e[SEQ];
__device__ float g_p[SEQ];
__device__ float g_invden[SEQ];
__device__ float g_csum[64 * HID];

// zero all tag-carrying buffers each launch: no cross-call state is relied upon
__global__ __launch_bounds__(256) void k_init()
{
  const size_t i = (size_t)blockIdx.x * 256 + threadIdx.x;   // 4096*256 = 1M threads
  const size_t base = i << 2;
#pragma unroll
  for (int k = 0; k < 4; k++) g_hstep[base + k] = 0ull;      // 4M words
  if (i < 2 * HID) ((u64*)g_h2p)[i] = 0ull;
  if (i < (size_t)UPL * HID) g_upxp[i] = 0ull;
}

// -------- coherent access via agent-scope relaxed atomics ----------------------
__device__ __forceinline__ u64 atomLoad64(const u64* p) {
  return __hip_atomic_load(p, __ATOMIC_RELAXED, __HIP_MEMORY_SCOPE_AGENT);
}
__device__ __forceinline__ void atomStore64(u64* p, u64 v) {
  __hip_atomic_store(p, v, __ATOMIC_RELAXED, __HIP_MEMORY_SCOPE_AGENT);
}
__device__ __forceinline__ u64 packPair(float v, unsigned tag) {
  return ((u64)tag << 32) | (u64)__float_as_uint(v);
}
// slow-path tagged poll (rare phases + fallback)
__device__ __forceinline__ float pollPair(const u64* p, unsigned tg) {
  u64 v = atomLoad64(p);
  while ((unsigned)(v >> 32) != tg) {
    __builtin_amdgcn_s_sleep(8);
    v = atomLoad64(p);
  }
  return __uint_as_float((unsigned)v);
}
// fast path: one PLAIN cached 8B load (fresh address -> never stale in L2 unless
// it raced; tag-check detects the race and falls back to coherent polling).
__device__ __forceinline__ float readPair(const u64* p, unsigned tg) {
  u64 v;
  asm volatile("global_load_dwordx2 %0, %1, off\n\t"
               "s_waitcnt vmcnt(0)"
               : "=v"(v) : "v"(p) : "memory");
  if ((unsigned)(v >> 32) == tg) return __uint_as_float((unsigned)v);
  return pollPair(p, tg);
}

// ---------------- K1: xg = x @ bot_Wih^T + (bih + bhh), fp32 tiled GEMM --------
#define BMT 128
#define BNT 128
#define BKT 32

__global__ __launch_bounds__(256) void k_gemm_xg(const float* __restrict__ A,
                                                 const float* __restrict__ B,
                                                 const float* __restrict__ bias0,
                                                 const float* __restrict__ bias1)
{
  __shared__ float As[BKT][BMT + 4];
  __shared__ float Bs[BKT][BNT + 4];
  const int t  = threadIdx.x;
  const int bn = blockIdx.x;
  const int bm = blockIdx.y;
  const int m0 = (t & 15) * 8;
  const int n0 = (t >> 4) * 8;

  float acc[8][8];
#pragma unroll
  for (int i = 0; i < 8; i++)
#pragma unroll
    for (int j = 0; j < 8; j++) acc[i][j] = 0.f;

  for (int k0 = 0; k0 < 1024; k0 += BKT) {
#pragma unroll
    for (int i = 0; i < 4; i++) {
      const int idx = i * 256 + t;
      const int m   = idx >> 3;
      const int k4  = (idx & 7) << 2;
      const float4 av = *(const float4*)&A[(size_t)(bm * BMT + m) * 1024 + k0 + k4];
      As[k4 + 0][m] = av.x; As[k4 + 1][m] = av.y; As[k4 + 2][m] = av.z; As[k4 + 3][m] = av.w;
      const float4 bv = *(const float4*)&B[(size_t)(bn * BNT + m) * 1024 + k0 + k4];
      Bs[k4 + 0][m] = bv.x; Bs[k4 + 1][m] = bv.y; Bs[k4 + 2][m] = bv.z; Bs[k4 + 3][m] = bv.w;
    }
    __syncthreads();
#pragma unroll
    for (int k = 0; k < BKT; k++) {
      float a[8], b[8];
      *(float4*)&a[0] = *(const float4*)&As[k][m0];
      *(float4*)&a[4] = *(const float4*)&As[k][m0 + 4];
      *(float4*)&b[0] = *(const float4*)&Bs[k][n0];
      *(float4*)&b[4] = *(const float4*)&Bs[k][n0 + 4];
#pragma unroll
      for (int i = 0; i < 8; i++)
#pragma unroll
        for (int j = 0; j < 8; j++) acc[i][j] = fmaf(a[i], b[j], acc[i][j]);
    }
    __syncthreads();
  }

  float bb[8];
#pragma unroll
  for (int j = 0; j < 8; j++) {
    const int gc = bn * BNT + n0 + j;
    bb[j] = bias0[gc] + bias1[gc];
  }
#pragma unroll
  for (int i = 0; i < 8; i++) {
    const size_t off = (size_t)(bm * BMT + m0 + i) * G4 + bn * BNT + n0;
    float4 v0, v1;
    v0.x = acc[i][0] + bb[0]; v0.y = acc[i][1] + bb[1]; v0.z = acc[i][2] + bb[2]; v0.w = acc[i][3] + bb[3];
    v1.x = acc[i][4] + bb[4]; v1.y = acc[i][5] + bb[5]; v1.z = acc[i][6] + bb[6]; v1.w = acc[i][7] + bb[7];
    *(float4*)&g_xg[off]     = v0;
    *(float4*)&g_xg[off + 4] = v1;
  }
}

// ---------------- K2: persistent LSTM, per-step fused-pair dataflow ------------
// Wave q of WG w owns hidden unit u = w*16+q. Lane l: gate g = l>>4, column
// segment j = l&15 (64 cols). Weights: 16 float4/lane in VGPRs.
// Publish: ONE fused 8B agent-atomic store per unit per step (no ack/flag/sync).
// Consume: calibrated s_sleep, ONE plain cached 8B load (fresh address per step),
// tag-check, atomic-poll fallback. ONE __syncthreads per step.

__device__ __forceinline__ void load_w16(float4* __restrict__ wv,
                                         const float* __restrict__ W,
                                         int row, int j)
{
  const float* wr = W + (size_t)row * HID + (j << 6);
#pragma unroll
  for (int k = 0; k < 16; k++) wv[k] = *(const float4*)&wr[((k + j) & 15) << 2];
}

__device__ __forceinline__ float dot16(const float4* __restrict__ wv,
                                       const float* __restrict__ hb, int j)
{
  float acc = 0.f;
#pragma unroll
  for (int k = 0; k < 16; k++) {
    const float4 hv = *(const float4*)&hb[((k + j) & 15) << 2];  // rotated
    acc = fmaf(wv[k].x, hv.x, acc);
    acc = fmaf(wv[k].y, hv.y, acc);
    acc = fmaf(wv[k].z, hv.z, acc);
    acc = fmaf(wv[k].w, hv.w, acc);
  }
  return acc;
}

__global__ __launch_bounds__(TPB, 4) void k_lstm(
    const float* __restrict__ bot_Whh,
    const float* __restrict__ top_Wih, const float* __restrict__ top_Whh,
    const float* __restrict__ top_bih, const float* __restrict__ top_bhh,
    const float* __restrict__ hw_b,    const float* __restrict__ cw_w,
    const float* __restrict__ cw_b,    const float* __restrict__ att_bias)
{
  const int w  = blockIdx.x;            // 0..63
  const int t  = threadIdx.x;           // 0..1023
  const int q  = t >> 6;                // wave 0..15
  const int l  = t & 63;
  const int g  = l >> 4;                // gate 0..3
  const int j  = l & 15;                // col segment 0..15
  const int u  = (w << 4) + q;          // owned hidden unit
  const int row = (g << 10) + u;        // gate*1024 + unit

  __shared__ float hl[2][HID];          // parity-double-buffered h stage
  __shared__ float xg2_lds[UPL][64];    // 16 units * 4 gates per WG

  float4 wv[16];
  load_w16(wv, bot_Whh, row, j);

  float c_state = 0.f;

  // ---- bottom LSTM: 4096 sequential steps ----
  for (int step = 0; step < SEQ; step++) {
    float xval = 0.f;
    if (j == 0) xval = g_xg[(size_t)step * G4 + row];   // overlaps the wait

    float* hc = hl[step & 1];
    if (step == 0) {
      hc[t] = 0.f;
    } else {
      __builtin_amdgcn_s_sleep(20);     // ~0.55us: let producers' stores land
      hc[t] = readPair(&g_hstep[((size_t)(step - 1) << 10) + t], (unsigned)step);
    }
    __syncthreads();

    float acc = dot16(wv, &hc[j << 6], j);
    acc += __shfl_xor(acc, 1);
    acc += __shfl_xor(acc, 2);
    acc += __shfl_xor(acc, 4);
    acc += __shfl_xor(acc, 8);
    acc += xval;                         // xval==0 on j!=0 lanes

    const float gi = __shfl(acc, 0);
    const float gf = __shfl(acc, 16);
    const float gg = __shfl(acc, 32);
    const float go = __shfl(acc, 48);
    const float ii = 1.f / (1.f + expf(-gi));
    const float ff = 1.f / (1.f + expf(-gf));
    c_state = ff * c_state + ii * tanhf(gg);
    const float hh = (1.f / (1.f + expf(-go))) * tanhf(c_state);

    if (l == 0) {
      atomStore64(&g_hstep[((size_t)step << 10) + u], packPair(hh, (unsigned)(step + 1)));
      g_y[(size_t)step * HID + u] = hh;
      if ((step & 63) == 63)
        atomStore64(&g_upxp[((size_t)(step >> 6) << 10) + u],
                    packPair(hh, (unsigned)((step >> 6) + 1)));
    }
  }

  // ---- top-LSTM input projection: xg2[s] = upx[s] @ top_Wih^T + bias ----
  load_w16(wv, top_Wih, row, j);
  float tb = 0.f;
  if (j == 0) tb = top_bih[row] + top_bhh[row];
  for (int s = 0; s < UPL; s++) {
    float* hc = hl[s & 1];
    hc[t] = pollPair(&g_upxp[((size_t)s << 10) + t], (unsigned)(s + 1));
    __syncthreads();
    float acc = dot16(wv, &hc[j << 6], j);
    acc += __shfl_xor(acc, 1);
    acc += __shfl_xor(acc, 2);
    acc += __shfl_xor(acc, 4);
    acc += __shfl_xor(acc, 8);
    if (j == 0) xg2_lds[s][(q << 2) + g] = acc + tb;
    __syncthreads();
  }

  // ---- top recurrence: 64 steps (tagged pairs; tiny) ----
  load_w16(wv, top_Whh, row, j);
  c_state = 0.f;
  for (int s = 0; s < UPL; s++) {
    float* hc = hl[s & 1];
    if (s == 0) {
      hc[t] = 0.f;
    } else {
      hc[t] = pollPair(&g_h2p[(s + 1) & 1][t], (unsigned)s);
    }
    __syncthreads();
    float acc = dot16(wv, &hc[j << 6], j);
    acc += __shfl_xor(acc, 1);
    acc += __shfl_xor(acc, 2);
    acc += __shfl_xor(acc, 4);
    acc += __shfl_xor(acc, 8);
    acc += xg2_lds[s][(q << 2) + g];     // uniform within 16-lane group

    const float gi = __shfl(acc, 0);
    const float gf = __shfl(acc, 16);
    const float gg = __shfl(acc, 32);
    const float go = __shfl(acc, 48);
    const float ii = 1.f / (1.f + expf(-gi));
    const float ff = 1.f / (1.f + expf(-gf));
    c_state = ff * c_state + ii * tanhf(gg);
    const float hh = (1.f / (1.f + expf(-go))) * tanhf(c_state);

    if (l == 0)
      atomStore64(&g_h2p[s & 1][u], packPair(hh, (unsigned)(s + 1)));
  }

  // ---- bias2[u] = hw_b + cw_b + att_bias + ctx @ cw_w^T (ctx = h2 @ s=63) ----
  {
    float* hc = hl[0];
    hc[t] = pollPair(&g_h2p[1][t], (unsigned)UPL);
    __syncthreads();

    const float* cr = cw_w + (size_t)u * HID + (l << 4);
    const float* hr = &hc[l << 4];
    float a2 = 0.f;
#pragma unroll
    for (int k4 = 0; k4 < 4; k4++) {
      const float4 cv = *(const float4*)&cr[k4 << 2];
      const float4 hv = *(const float4*)&hr[k4 << 2];
      a2 = fmaf(cv.x, hv.x, a2);
      a2 = fmaf(cv.y, hv.y, a2);
      a2 = fmaf(cv.z, hv.z, a2);
      a2 = fmaf(cv.w, hv.w, a2);
    }
    a2 += __shfl_xor(a2, 1);
    a2 += __shfl_xor(a2, 2);
    a2 += __shfl_xor(a2, 4);
    a2 += __shfl_xor(a2, 8);
    a2 += __shfl_xor(a2, 16);
    a2 += __shfl_xor(a2, 32);
    if (l == 0) g_bias2[u] = a2 + hw_b[u] + cw_b[u] + att_bias[u];
  }
}

// ---------------- K3: e[t] = sum_j v2s_w[j]*tanh(y_t . hw_w[j] + bias2[j]) ----
__global__ __launch_bounds__(256) void k_attn_e(const float* __restrict__ hw_w,
                                                const float* __restrict__ v2s_w,
                                                const float* __restrict__ v2s_b)
{
  __shared__ float ys[16][1028];
  __shared__ float ws[16][1028];
  const int b  = blockIdx.x;
  const int t  = threadIdx.x;
  const int rg = t >> 6;
  const int fg = (t >> 4) & 3;
  const int ks = t & 15;

#pragma unroll
  for (int i = 0; i < 16; i++) {
    const int idx = i * 256 + t;
    const int r   = idx >> 8;
    const int c4  = (idx & 255) << 2;
    *(float4*)&ys[r][c4] = *(const float4*)&g_y[(size_t)((b << 4) + r) * HID + c4];
  }

  float e_acc[4] = {0.f, 0.f, 0.f, 0.f};
  for (int f0 = 0; f0 < HID; f0 += 16) {
    __syncthreads();
#pragma unroll
    for (int i = 0; i < 16; i++) {
      const int idx = i * 256 + t;
      const int r   = idx >> 8;
      const int c4  = (idx & 255) << 2;
      *(float4*)&ws[r][c4] = *(const float4*)&hw_w[(size_t)(f0 + r) * HID + c4];
    }
    __syncthreads();

    float acc[4][4];
#pragma unroll
    for (int u = 0; u < 4; u++)
#pragma unroll
      for (int v = 0; v < 4; v++) acc[u][v] = 0.f;

#pragma unroll
    for (int m = 0; m < 16; m++) {
      const int k4 = (ks << 6) + (((m + ks) & 15) << 2);
      float4 av[4], bv[4];
#pragma unroll
      for (int u = 0; u < 4; u++) av[u] = *(const float4*)&ys[(rg << 2) + u][k4];
#pragma unroll
      for (int v = 0; v < 4; v++) bv[v] = *(const float4*)&ws[(fg << 2) + v][k4];
#pragma unroll
      for (int u = 0; u < 4; u++)
#pragma unroll
        for (int v = 0; v < 4; v++) {
          acc[u][v] = fmaf(av[u].x, bv[v].x, acc[u][v]);
          acc[u][v] = fmaf(av[u].y, bv[v].y, acc[u][v]);
          acc[u][v] = fmaf(av[u].z, bv[v].z, acc[u][v]);
          acc[u][v] = fmaf(av[u].w, bv[v].w, acc[u][v]);
        }
    }
#pragma unroll
    for (int u = 0; u < 4; u++)
#pragma unroll
      for (int v = 0; v < 4; v++) {
        float s2 = acc[u][v];
        s2 += __shfl_xor(s2, 8);
        s2 += __shfl_xor(s2, 4);
        s2 += __shfl_xor(s2, 2);
        s2 += __shfl_xor(s2, 1);
        acc[u][v] = s2;
      }
    if (ks == 0) {
#pragma unroll
      for (int v = 0; v < 4; v++) {
        const int jj = f0 + (fg << 2) + v;
        const float bias = g_bias2[jj];
        const float vw   = v2s_w[jj];
#pragma unroll
        for (int u = 0; u < 4; u++)
          e_acc[u] += vw * tanhf(acc[u][v] + bias);
      }
    }
  }
#pragma unroll
  for (int u = 0; u < 4; u++) {
    float s2 = e_acc[u];
    s2 += __shfl_xor(s2, 16);
    s2 += __shfl_xor(s2, 32);
    if (fg == 0 && ks == 0) g_e[(b << 4) + (rg << 2) + u] = s2 + v2s_b[0];
  }
}

// ---------------- K4a: p = exp(e - max e); invden = 1/cumsum(p) --------------
__global__ __launch_bounds__(1024) void k_softmax()
{
  const int t  = threadIdx.x;
  const int ln = t & 63;
  const int wv = t >> 6;
  __shared__ float sred[16];
  __shared__ float soff[16];
  __shared__ float sM;

  const float4 ev = *(const float4*)&g_e[t << 2];
  float mx = fmaxf(fmaxf(ev.x, ev.y), fmaxf(ev.z, ev.w));
#pragma unroll
  for (int d = 32; d >= 1; d >>= 1) mx = fmaxf(mx, __shfl_xor(mx, d));
  if (ln == 0) sred[wv] = mx;
  __syncthreads();
  if (t == 0) {
    float m2 = sred[0];
    for (int i = 1; i < 16; i++) m2 = fmaxf(m2, sred[i]);
    sM = m2;
  }
  __syncthreads();
  const float M = sM;
  float4 pv;
  pv.x = expf(ev.x - M); pv.y = expf(ev.y - M); pv.z = expf(ev.z - M); pv.w = expf(ev.w - M);
  *(float4*)&g_p[t << 2] = pv;

  const float s = pv.x + pv.y + pv.z + pv.w;
  float ps = s;
#pragma unroll
  for (int d = 1; d < 64; d <<= 1) {
    const float v = __shfl_up(ps, d);
    if (ln >= d) ps += v;
  }
  __syncthreads();
  if (ln == 63) sred[wv] = ps;
  __syncthreads();
  if (t == 0) {
    float r = 0.f;
    for (int i = 0; i < 16; i++) { soff[i] = r; r += sred[i]; }
  }
  __syncthreads();
  const float base = soff[wv] + (ps - s);
  const float d0 = base + pv.x;
  const float d1 = d0 + pv.y;
  const float d2 = d1 + pv.z;
  const float d3 = d2 + pv.w;
  float4 iv;
  iv.x = 1.f / d0; iv.y = 1.f / d1; iv.z = 1.f / d2; iv.w = 1.f / d3;
  *(float4*)&g_invden[t << 2] = iv;
}

// ---------------- K4b/c/d: chunked column scan of cumsum(p*y)/den ------------
__global__ __launch_bounds__(256) void k_csum()
{
  const int ch = blockIdx.x;
  const int t  = threadIdx.x;
  float ax = 0.f, ay = 0.f, az = 0.f, aw = 0.f;
  for (int r = 0; r < 64; r++) {
    const int row = (ch << 6) + r;
    const float pr = g_p[row];
    const float4 yv = *(const float4*)&g_y[(size_t)row * HID + (t << 2)];
    ax = fmaf(pr, yv.x, ax); ay = fmaf(pr, yv.y, ay);
    az = fmaf(pr, yv.z, az); aw = fmaf(pr, yv.w, aw);
  }
  float4 o; o.x = ax; o.y = ay; o.z = az; o.w = aw;
  *(float4*)&g_csum[(ch << 10) + (t << 2)] = o;
}

__global__ __launch_bounds__(256) void k_cscan()
{
  const int c = blockIdx.x * 256 + threadIdx.x;
  float run = 0.f;
  for (int ch = 0; ch < 64; ch++) {
    const float v = g_csum[(ch << 10) + c];
    g_csum[(ch << 10) + c] = run;
    run += v;
  }
}

__global__ __launch_bounds__(256) void k_final(float* __restrict__ out)
{
  const int ch = blockIdx.x;
  const int t  = threadIdx.x;
  float4 run = *(const float4*)&g_csum[(ch << 10) + (t << 2)];
  for (int r = 0; r < 64; r++) {
    const int row = (ch << 6) + r;
    const float pr = g_p[row];
    const float iv = g_invden[row];
    const float4 yv = *(const float4*)&g_y[(size_t)row * HID + (t << 2)];
    run.x = fmaf(pr, yv.x, run.x);
    run.y = fmaf(pr, yv.y, run.y);
    run.z = fmaf(pr, yv.z, run.z);
    run.w = fmaf(pr, yv.w, run.w);
    float4 ov;
    ov.x = run.x * iv; ov.y = run.y * iv; ov.z = run.z * iv; ov.w = run.w * iv;
    *(float4*)&out[(size_t)row * HID + (t << 2)] = ov;
  }
}

// ---------------- host launch --------------------------------------------------
extern "C" void kernel_launch(void* const* d_in, const int* in_sizes, int n_in,
                              void* d_out, int out_size, void* d_ws, size_t ws_size,
                              hipStream_t stream)
{
  (void)in_sizes; (void)n_in; (void)d_ws; (void)ws_size; (void)out_size;

  const float* x        = (const float*)d_in[0];
  const float* bot_Wih  = (const float*)d_in[1];
  const float* bot_Whh  = (const float*)d_in[2];
  const float* bot_bih  = (const float*)d_in[3];
  const float* bot_bhh  = (const float*)d_in[4];
  const float* top_Wih  = (const float*)d_in[5];
  const float* top_Whh  = (const float*)d_in[6];
  const float* top_bih  = (const float*)d_in[7];
  const float* top_bhh  = (const float*)d_in[8];
  const float* hw_w     = (const float*)d_in[9];
  const float* hw_b     = (const float*)d_in[10];
  const float* cw_w     = (const float*)d_in[11];
  const float* cw_b     = (const float*)d_in[12];
  const float* att_bias = (const float*)d_in[13];
  const float* v2s_w    = (const float*)d_in[14];
  const float* v2s_b    = (const float*)d_in[15];
  float* out = (float*)d_out;

  k_init<<<dim3(4096), dim3(256), 0, stream>>>();
  k_gemm_xg<<<dim3(32, 32), dim3(256), 0, stream>>>(x, bot_Wih, bot_bih, bot_bhh);
  k_lstm<<<dim3(NWG), dim3(TPB), 0, stream>>>(bot_Whh, top_Wih, top_Whh,
                                              top_bih, top_bhh,
                                              hw_b, cw_w, cw_b, att_bias);
  k_attn_e<<<dim3(256), dim3(256), 0, stream>>>(hw_w, v2s_w, v2s_b);
  k_softmax<<<dim3(1), dim3(1024), 0, stream>>>();
  k_csum<<<dim3(64), dim3(256), 0, stream>>>();
  k_cscan<<<dim3(4), dim3(256), 0, stream>>>();
  k_final<<<dim3(64), dim3(256), 0, stream>>>(out);
}